// Round 8
// baseline (295.021 us; speedup 1.0000x reference)
//
#include <hip/hip_runtime.h>

// Shapes fixed by the reference.
#define N_  64
#define T_  4096
#define D_  128
#define TS_ 16            // t's per slab-block
#define SL_ (T_ / TS_)    // 256 slabs

// ---------------------------------------------------------------------------
// Slab kernel: block = contiguous t-slab [t0, t0+16) x ALL 64 n.
// WHY (round-7 evidence): block-per-(n,chunk) pins every access to byte
// offset n*512 mod 32KB (t-stride is exactly 32KB) -> each block drives ~2
// HBM channels / L3 slices; BW capped at 2.78 TB/s regardless of ILP or
// occupancy. A slab block reads 512KB of K and 512KB of V CONTIGUOUSLY:
// its 8 half-waves sit at 8 different 4KB-spaced offsets -> all channels.
//
// Half-wave h (tid>>5) owns n in [h*8, h*8+8). Per n: 16 K rows -> dot with
// Q[n] (5-shfl half-wave reduce) -> per-slab max/exp/sum -> 16 V rows
// weighted into float4 acc. Partial (m, s, acc[d]) per (n, slab) to ws.
// V loads issued before the reduce chains so HBM latency hides under them.
// No __syncthreads anywhere: half-waves are fully independent.
// ---------------------------------------------------------------------------
__global__ __launch_bounds__(256) void slab_kernel(
    const float* __restrict__ key, const float* __restrict__ value,
    const float* __restrict__ query, const int* __restrict__ slen,
    float* __restrict__ mask_out, float* __restrict__ m_ws,
    float* __restrict__ s_ws, float* __restrict__ acc_ws)
{
    const int slab = blockIdx.x;
    const int t0   = slab * TS_;
    const int tid  = threadIdx.x;
    const int h    = tid >> 5;        // half-wave 0..7
    const int hl   = tid & 31;        // lane within half-wave

    // Preload the 8 Q rows this half-wave needs (32KB of Q is L2-hot).
    float4 qb[8];
    #pragma unroll
    for (int j = 0; j < 8; ++j)
        qb[j] = *reinterpret_cast<const float4*>(query + (h * 8 + j) * D_ + hl * 4);

    const size_t st = (size_t)N_ * D_;          // one t step = 8192 floats = 32KB

    for (int j = 0; j < 8; ++j) {
        const int n   = h * 8 + j;
        const int len = slen[n];
        const float4 qj = qb[j];
        const float* kr = key   + ((size_t)t0 * N_ + n) * D_ + hl * 4;
        const float* vr = value + ((size_t)t0 * N_ + n) * D_ + hl * 4;

        // Issue ALL 32 loads (16 K + 16 V rows) before any dependent compute.
        float4 kb[TS_];
        #pragma unroll
        for (int t = 0; t < TS_; ++t)
            kb[t] = *reinterpret_cast<const float4*>(kr + (size_t)t * st);
        float4 vb[TS_];
        #pragma unroll
        for (int t = 0; t < TS_; ++t)
            vb[t] = *reinterpret_cast<const float4*>(vr + (size_t)t * st);

        // Energies: dot + 5-shfl half-wave reduce; multiplicative mask -> 0.
        float e[TS_];
        #pragma unroll
        for (int t = 0; t < TS_; ++t) {
            float p = kb[t].x * qj.x + kb[t].y * qj.y
                    + kb[t].z * qj.z + kb[t].w * qj.w;
            #pragma unroll
            for (int off = 16; off; off >>= 1) p += __shfl_xor(p, off, 64);
            e[t] = (t0 + t < len) ? p : 0.f;
        }

        // Per-(n, slab) softmax partial.
        float m = e[0];
        #pragma unroll
        for (int t = 1; t < TS_; ++t) m = fmaxf(m, e[t]);
        float s = 0.f;
        #pragma unroll
        for (int t = 0; t < TS_; ++t) { e[t] = __expf(e[t] - m); s += e[t]; }

        // Weighted V accumulation (from registers).
        float4 a = make_float4(0.f, 0.f, 0.f, 0.f);
        #pragma unroll
        for (int t = 0; t < TS_; ++t) {
            a.x += e[t] * vb[t].x; a.y += e[t] * vb[t].y;
            a.z += e[t] * vb[t].z; a.w += e[t] * vb[t].w;
        }

        if (hl == 0) { m_ws[n * SL_ + slab] = m; s_ws[n * SL_ + slab] = s; }
        *reinterpret_cast<float4*>(acc_ws + ((size_t)n * SL_ + slab) * D_ + hl * 4) = a;
        if (hl < TS_)
            mask_out[n * T_ + t0 + hl] = (t0 + hl < len) ? 1.f : 0.f;
    }
}

// ---------------------------------------------------------------------------
// Finalize: per n combine 256 slab partials.
//   M = max_s m_s; w_s = exp(m_s-M); S = sum_s s_s*w_s;
//   ctx[n,d] = (1/S) * sum_s w_s * acc[n,s,d]
// 64 blocks x 256 threads; acc[n] is 128KB contiguous -> coalesced.
// ---------------------------------------------------------------------------
__global__ __launch_bounds__(256) void finalize_kernel(
    const float* __restrict__ m_ws, const float* __restrict__ s_ws,
    const float* __restrict__ acc_ws, float* __restrict__ ctx)
{
    const int n    = blockIdx.x;
    const int tid  = threadIdx.x;
    const int lane = tid & 63;
    const int wv   = tid >> 6;

    __shared__ float w[SL_];
    __shared__ float red[8];
    __shared__ float2 red2[4][64];

    // Block max of the 256 slab maxima (one per thread).
    const float mv = m_ws[n * SL_ + tid];
    float m = mv;
    #pragma unroll
    for (int off = 32; off; off >>= 1) m = fmaxf(m, __shfl_xor(m, off, 64));
    if (lane == 0) red[wv] = m;
    __syncthreads();
    const float M = fmaxf(fmaxf(red[0], red[1]), fmaxf(red[2], red[3]));

    const float wgt = __expf(mv - M);
    w[tid] = wgt;
    float sv = s_ws[n * SL_ + tid] * wgt;
    #pragma unroll
    for (int off = 32; off; off >>= 1) sv += __shfl_xor(sv, off, 64);
    if (lane == 0) red[4 + wv] = sv;
    __syncthreads();                    // publishes w[] and red[4..7]
    const float S = red[4] + red[5] + red[6] + red[7];

    // Weighted accumulation over slabs, 4 s-groups x 64 d-pairs.
    const float2* acc2 = reinterpret_cast<const float2*>(acc_ws);
    const int d2 = tid & 63;            // d-pair index (covers d = 2*d2, 2*d2+1)
    const int sg = tid >> 6;            // 0..3
    float2 r = make_float2(0.f, 0.f);
    #pragma unroll 8
    for (int s = sg; s < SL_; s += 4) {
        const float ws_ = w[s];
        const float2 a = acc2[((size_t)n * SL_ + s) * (D_ / 2) + d2];
        r.x += ws_ * a.x; r.y += ws_ * a.y;
    }
    red2[sg][d2] = r;
    __syncthreads();
    if (sg == 0) {
        const float2 a = red2[0][d2], b = red2[1][d2];
        const float2 c = red2[2][d2], d = red2[3][d2];
        const float invS = 1.f / S;
        float2 o;
        o.x = ((a.x + b.x) + (c.x + d.x)) * invS;
        o.y = ((a.y + b.y) + (c.y + d.y)) * invS;
        *reinterpret_cast<float2*>(ctx + n * D_ + d2 * 2) = o;
    }
}

// ---------------------------------------------------------------------------
extern "C" void kernel_launch(void* const* d_in, const int* in_sizes, int n_in,
                              void* d_out, int out_size, void* d_ws, size_t ws_size,
                              hipStream_t stream) {
    const float* query = (const float*)d_in[0];   // (N, D)
    const float* key   = (const float*)d_in[1];   // (T, N, D)
    const float* value = (const float*)d_in[2];   // (T, N, D)
    const int*   slen  = (const int*)d_in[3];     // (N,)

    float* out      = (float*)d_out;
    float* ctx_out  = out;                // N*D floats
    float* mask_out = out + N_ * D_;      // N*T floats

    float* m_ws   = (float*)d_ws;                 // N*SL floats
    float* s_ws   = m_ws + N_ * SL_;              // N*SL floats
    float* acc_ws = s_ws + N_ * SL_;              // N*SL*D floats (8MB)

    slab_kernel<<<SL_, 256, 0, stream>>>(key, value, query, slen,
                                         mask_out, m_ws, s_ws, acc_ws);
    finalize_kernel<<<N_, 256, 0, stream>>>(m_ws, s_ws, acc_ws, ctx_out);
}

// Round 9
// 290.456 us; speedup vs baseline: 1.0157x; 1.0157x over previous
//
#include <hip/hip_runtime.h>

// Shapes fixed by the reference.
#define N_  64
#define T_  4096
#define D_  128

// ---------------------------------------------------------------------------
// Energy: e[n,t] = <key[t,n,:], q[n,:]>, masked (t>=len -> 0).
// SINGLE-SEGMENT loads (the round-8 A/B): one wave-load = 1KB CONTIGUOUS
// covering rows (t,n0) [lanes 0-31] and (t,n0+1) [lanes 32-63] — key[t] is a
// contiguous 64x128 block, so n0 and n0+1 rows are adjacent. All prior rounds
// used 2x512B split segments and were pinned at ~2.7 TB/s effective.
// Wave w: npair = w&31 (fixed), t walks 16 steps; 8-deep prefetch.
// 2048 blocks x 256 thr = 8192 waves = 131072 row-pairs = all (t, npair).
// ---------------------------------------------------------------------------
__global__ __launch_bounds__(256) void energy_kernel(
    const float* __restrict__ key, const float* __restrict__ query,
    const int* __restrict__ slen, float* __restrict__ energy)
{
    const int tid   = threadIdx.x;
    const int lane  = tid & 63;
    const int wv    = tid >> 6;
    const int w     = blockIdx.x * 4 + wv;
    const int npair = w & 31;
    const int t0    = (w >> 5) << 4;       // 16 t's per wave
    const int nl    = lane >> 5;           // 0 or 1
    const int d4    = lane & 31;           // float4 index within row
    const int n     = npair * 2 + nl;
    const int len   = slen[n];

    const float4 q4 = *reinterpret_cast<const float4*>(query + n * D_ + d4 * 4);
    // lane*4 floats = nl*512B + d4*16B -> contiguous 1KB across the wave.
    const float* kbase = key + ((size_t)t0 * N_ + npair * 2) * D_ + lane * 4;
    const size_t st = (size_t)N_ * D_;     // t-stride in floats (32KB)

    float4 kb[8];
    #pragma unroll
    for (int g = 0; g < 2; ++g) {
        #pragma unroll
        for (int i = 0; i < 8; ++i)
            kb[i] = *reinterpret_cast<const float4*>(kbase + (size_t)(g * 8 + i) * st);
        #pragma unroll
        for (int i = 0; i < 8; ++i) {
            float p = kb[i].x * q4.x + kb[i].y * q4.y
                    + kb[i].z * q4.z + kb[i].w * q4.w;
            #pragma unroll
            for (int off = 16; off; off >>= 1) p += __shfl_xor(p, off, 64);
            const int t = t0 + g * 8 + i;
            if (d4 == 0) energy[(size_t)n * T_ + t] = (t < len) ? p : 0.f;
        }
    }
}

// ---------------------------------------------------------------------------
// Softmax over t per n (exact, in-place on energy buffer) + mask output.
// One block per n. Masked positions hold 0 (multiplicative-mask semantics:
// they contribute exp(0-m) and their V rows DO count in the context).
// ---------------------------------------------------------------------------
__global__ __launch_bounds__(256) void softmax_kernel(
    float* __restrict__ energy_score, const int* __restrict__ slen,
    float* __restrict__ mask_out)
{
    const int n    = blockIdx.x;
    const int len  = slen[n];
    const int tid  = threadIdx.x;
    const int lane = tid & 63;
    const int wv   = tid >> 6;

    float ev[T_ / 256];
    #pragma unroll
    for (int i = 0; i < T_ / 256; ++i)
        ev[i] = energy_score[(size_t)n * T_ + tid + i * 256];   // already masked

    float m = -3.4e38f;
    #pragma unroll
    for (int i = 0; i < T_ / 256; ++i) m = fmaxf(m, ev[i]);
    #pragma unroll
    for (int off = 32; off; off >>= 1) m = fmaxf(m, __shfl_xor(m, off, 64));
    __shared__ float wred[8];
    if (lane == 0) wred[wv] = m;
    __syncthreads();
    m = fmaxf(fmaxf(wred[0], wred[1]), fmaxf(wred[2], wred[3]));

    float s = 0.f;
    #pragma unroll
    for (int i = 0; i < T_ / 256; ++i) s += __expf(ev[i] - m);
    #pragma unroll
    for (int off = 32; off; off >>= 1) s += __shfl_xor(s, off, 64);
    if (lane == 0) wred[4 + wv] = s;
    __syncthreads();
    s = wred[4] + wred[5] + wred[6] + wred[7];
    const float inv = 1.f / s;

    #pragma unroll
    for (int i = 0; i < T_ / 256; ++i) {
        const int t = tid + i * 256;
        energy_score[(size_t)n * T_ + t] = __expf(ev[i] - m) * inv;
        mask_out[(size_t)n * T_ + t] = (t < len) ? 1.f : 0.f;
    }
}

// ---------------------------------------------------------------------------
// PV: part[c, npair, nl, :] = sum_{t in chunk c} score[n,t] * value[t,n,:].
// Same single-segment 1KB load shape as energy_kernel. Block b = (c, npair),
// wave g covers 16 t's; LDS-reduce 4 waves -> 1KB coalesced partial store.
// ---------------------------------------------------------------------------
__global__ __launch_bounds__(256) void pv_kernel(
    const float* __restrict__ value, const float* __restrict__ score,
    float* __restrict__ part)
{
    const int b     = blockIdx.x;          // 2048 = 64 chunks x 32 npairs
    const int npair = b & 31;
    const int c     = b >> 5;              // t-chunk 0..63
    const int tid   = threadIdx.x;
    const int lane  = tid & 63;
    const int g     = tid >> 6;            // wave 0..3
    const int nl    = lane >> 5;
    const int d4    = lane & 31;
    const int n     = npair * 2 + nl;
    const int t0    = c * 64 + g * 16;

    const float* vbase = value + ((size_t)t0 * N_ + npair * 2) * D_ + lane * 4;
    const size_t st = (size_t)N_ * D_;

    float4 acc = make_float4(0.f, 0.f, 0.f, 0.f);
    float4 vb[8];
    #pragma unroll
    for (int gg = 0; gg < 2; ++gg) {
        #pragma unroll
        for (int i = 0; i < 8; ++i)
            vb[i] = *reinterpret_cast<const float4*>(vbase + (size_t)(gg * 8 + i) * st);
        #pragma unroll
        for (int i = 0; i < 8; ++i) {
            const float sc = score[(size_t)n * T_ + t0 + gg * 8 + i];  // L1/L2-hot
            acc.x += sc * vb[i].x; acc.y += sc * vb[i].y;
            acc.z += sc * vb[i].z; acc.w += sc * vb[i].w;
        }
    }

    __shared__ float4 red[4][64];
    red[g][lane] = acc;
    __syncthreads();
    if (tid < 64) {
        const float4 a = red[0][tid], bb = red[1][tid];
        const float4 cc = red[2][tid], dd = red[3][tid];
        float4 r;
        r.x = (a.x + bb.x) + (cc.x + dd.x);
        r.y = (a.y + bb.y) + (cc.y + dd.y);
        r.z = (a.z + bb.z) + (cc.z + dd.z);
        r.w = (a.w + bb.w) + (cc.w + dd.w);
        *reinterpret_cast<float4*>(part + ((size_t)b * 2 + (tid >> 5)) * D_
                                        + (tid & 31) * 4) = r;
    }
}

// ---------------------------------------------------------------------------
// Final reduce: ctx[n,:] = sum_c part[c, n>>1, n&1, :]  (score pre-normalized).
// ---------------------------------------------------------------------------
__global__ __launch_bounds__(128) void ctx_reduce_kernel(
    const float* __restrict__ part, float* __restrict__ ctx)
{
    const int n = blockIdx.x;
    const int d = threadIdx.x;
    const int npair = n >> 1, nl = n & 1;
    float a = 0.f;
    #pragma unroll 8
    for (int c = 0; c < 64; ++c)
        a += part[(((size_t)c * 32 + npair) * 2 + nl) * D_ + d];
    ctx[(size_t)n * D_ + d] = a;
}

// ---------------------------------------------------------------------------
extern "C" void kernel_launch(void* const* d_in, const int* in_sizes, int n_in,
                              void* d_out, int out_size, void* d_ws, size_t ws_size,
                              hipStream_t stream) {
    const float* query = (const float*)d_in[0];   // (N, D)
    const float* key   = (const float*)d_in[1];   // (T, N, D)
    const float* value = (const float*)d_in[2];   // (T, N, D)
    const int*   slen  = (const int*)d_in[3];     // (N,)

    float* out      = (float*)d_out;
    float* ctx_out  = out;                // N*D floats
    float* mask_out = out + N_ * D_;      // N*T floats

    float* energy_score = (float*)d_ws;               // N*T floats (1MB)
    float* part         = energy_score + (size_t)N_ * T_;  // 64*32*2*128 floats (2MB)

    energy_kernel<<<2048, 256, 0, stream>>>(key, query, slen, energy_score);
    softmax_kernel<<<N_, 256, 0, stream>>>(energy_score, slen, mask_out);
    pv_kernel<<<2048, 256, 0, stream>>>(value, energy_score, part);
    ctx_reduce_kernel<<<N_, 128, 0, stream>>>(part, ctx_out);
}

// Round 10
// 268.337 us; speedup vs baseline: 1.0994x; 1.0824x over previous
//
#include <hip/hip_runtime.h>

// Shapes fixed by the reference.
#define N_  64
#define T_  4096
#define D_  128

// Non-temporal float4 load: stream past cache allocation (nt flag).
typedef float f4v __attribute__((ext_vector_type(4)));
__device__ __forceinline__ f4v nt_load4(const float* p) {
    return __builtin_nontemporal_load(reinterpret_cast<const f4v*>(p));
}

// ---------------------------------------------------------------------------
// Energy: e[n,t] = <key[t,n,:], q[n,:]>, masked (t>=len -> 0).
// Round-10 single-variable change vs round 9: K loads are NON-TEMPORAL.
// (Round 6-9 established a ~2.6 TB/s read wall invariant to occupancy, ILP,
// segment shape, and block address coverage; the untested variable is the
// cache path — harness restore leaves K/V L3-resident and read-hits may be
// the throttle.)
// One wave-load = 1KB contiguous: rows (t,n0) lanes 0-31, (t,n0+1) lanes
// 32-63. Wave w: npair = w&31, t walks 16 steps, 8-deep prefetch.
// ---------------------------------------------------------------------------
__global__ __launch_bounds__(256) void energy_kernel(
    const float* __restrict__ key, const float* __restrict__ query,
    const int* __restrict__ slen, float* __restrict__ energy)
{
    const int tid   = threadIdx.x;
    const int lane  = tid & 63;
    const int wv    = tid >> 6;
    const int w     = blockIdx.x * 4 + wv;
    const int npair = w & 31;
    const int t0    = (w >> 5) << 4;       // 16 t's per wave
    const int d4    = lane & 31;           // float4 index within row
    const int n     = npair * 2 + (lane >> 5);
    const int len   = slen[n];

    const float4 q4 = *reinterpret_cast<const float4*>(query + n * D_ + d4 * 4);
    const float* kbase = key + ((size_t)t0 * N_ + npair * 2) * D_ + lane * 4;
    const size_t st = (size_t)N_ * D_;     // t-stride in floats (32KB)

    f4v kb[8];
    #pragma unroll
    for (int g = 0; g < 2; ++g) {
        #pragma unroll
        for (int i = 0; i < 8; ++i)
            kb[i] = nt_load4(kbase + (size_t)(g * 8 + i) * st);
        #pragma unroll
        for (int i = 0; i < 8; ++i) {
            float p = kb[i][0] * q4.x + kb[i][1] * q4.y
                    + kb[i][2] * q4.z + kb[i][3] * q4.w;
            #pragma unroll
            for (int off = 16; off; off >>= 1) p += __shfl_xor(p, off, 64);
            const int t = t0 + g * 8 + i;
            if (d4 == 0) energy[(size_t)n * T_ + t] = (t < len) ? p : 0.f;
        }
    }
}

// ---------------------------------------------------------------------------
// Softmax over t per n (exact, in-place on energy buffer) + mask output.
// Masked positions hold 0 (multiplicative-mask semantics).
// ---------------------------------------------------------------------------
__global__ __launch_bounds__(256) void softmax_kernel(
    float* __restrict__ energy_score, const int* __restrict__ slen,
    float* __restrict__ mask_out)
{
    const int n    = blockIdx.x;
    const int len  = slen[n];
    const int tid  = threadIdx.x;
    const int lane = tid & 63;
    const int wv   = tid >> 6;

    float ev[T_ / 256];
    #pragma unroll
    for (int i = 0; i < T_ / 256; ++i)
        ev[i] = energy_score[(size_t)n * T_ + tid + i * 256];   // already masked

    float m = -3.4e38f;
    #pragma unroll
    for (int i = 0; i < T_ / 256; ++i) m = fmaxf(m, ev[i]);
    #pragma unroll
    for (int off = 32; off; off >>= 1) m = fmaxf(m, __shfl_xor(m, off, 64));
    __shared__ float wred[8];
    if (lane == 0) wred[wv] = m;
    __syncthreads();
    m = fmaxf(fmaxf(wred[0], wred[1]), fmaxf(wred[2], wred[3]));

    float s = 0.f;
    #pragma unroll
    for (int i = 0; i < T_ / 256; ++i) s += __expf(ev[i] - m);
    #pragma unroll
    for (int off = 32; off; off >>= 1) s += __shfl_xor(s, off, 64);
    if (lane == 0) wred[4 + wv] = s;
    __syncthreads();
    s = wred[4] + wred[5] + wred[6] + wred[7];
    const float inv = 1.f / s;

    #pragma unroll
    for (int i = 0; i < T_ / 256; ++i) {
        const int t = tid + i * 256;
        energy_score[(size_t)n * T_ + t] = __expf(ev[i] - m) * inv;
        mask_out[(size_t)n * T_ + t] = (t < len) ? 1.f : 0.f;
    }
}

// ---------------------------------------------------------------------------
// PV: part[c, npair, nl, :] = sum_{t in chunk c} score[n,t] * value[t,n,:].
// V loads NON-TEMPORAL (the 128MB stream); score reads stay cached (hot).
// ---------------------------------------------------------------------------
__global__ __launch_bounds__(256) void pv_kernel(
    const float* __restrict__ value, const float* __restrict__ score,
    float* __restrict__ part)
{
    const int b     = blockIdx.x;          // 2048 = 64 chunks x 32 npairs
    const int npair = b & 31;
    const int c     = b >> 5;              // t-chunk 0..63
    const int tid   = threadIdx.x;
    const int lane  = tid & 63;
    const int g     = tid >> 6;            // wave 0..3
    const int n     = npair * 2 + (lane >> 5);
    const int t0    = c * 64 + g * 16;

    const float* vbase = value + ((size_t)t0 * N_ + npair * 2) * D_ + lane * 4;
    const size_t st = (size_t)N_ * D_;

    float4 acc = make_float4(0.f, 0.f, 0.f, 0.f);
    f4v vb[8];
    #pragma unroll
    for (int gg = 0; gg < 2; ++gg) {
        #pragma unroll
        for (int i = 0; i < 8; ++i)
            vb[i] = nt_load4(vbase + (size_t)(gg * 8 + i) * st);
        #pragma unroll
        for (int i = 0; i < 8; ++i) {
            const float sc = score[(size_t)n * T_ + t0 + gg * 8 + i];  // L1/L2-hot
            acc.x += sc * vb[i][0]; acc.y += sc * vb[i][1];
            acc.z += sc * vb[i][2]; acc.w += sc * vb[i][3];
        }
    }

    __shared__ float4 red[4][64];
    red[g][lane] = acc;
    __syncthreads();
    if (tid < 64) {
        const float4 a = red[0][tid], bb = red[1][tid];
        const float4 cc = red[2][tid], dd = red[3][tid];
        float4 r;
        r.x = (a.x + bb.x) + (cc.x + dd.x);
        r.y = (a.y + bb.y) + (cc.y + dd.y);
        r.z = (a.z + bb.z) + (cc.z + dd.z);
        r.w = (a.w + bb.w) + (cc.w + dd.w);
        *reinterpret_cast<float4*>(part + ((size_t)b * 2 + (tid >> 5)) * D_
                                        + (tid & 31) * 4) = r;
    }
}

// ---------------------------------------------------------------------------
// Final reduce: ctx[n,:] = sum_c part[c, n>>1, n&1, :]  (score pre-normalized).
// ---------------------------------------------------------------------------
__global__ __launch_bounds__(128) void ctx_reduce_kernel(
    const float* __restrict__ part, float* __restrict__ ctx)
{
    const int n = blockIdx.x;
    const int d = threadIdx.x;
    const int npair = n >> 1, nl = n & 1;
    float a = 0.f;
    #pragma unroll 8
    for (int c = 0; c < 64; ++c)
        a += part[(((size_t)c * 32 + npair) * 2 + nl) * D_ + d];
    ctx[(size_t)n * D_ + d] = a;
}

// ---------------------------------------------------------------------------
extern "C" void kernel_launch(void* const* d_in, const int* in_sizes, int n_in,
                              void* d_out, int out_size, void* d_ws, size_t ws_size,
                              hipStream_t stream) {
    const float* query = (const float*)d_in[0];   // (N, D)
    const float* key   = (const float*)d_in[1];   // (T, N, D)
    const float* value = (const float*)d_in[2];   // (T, N, D)
    const int*   slen  = (const int*)d_in[3];     // (N,)

    float* out      = (float*)d_out;
    float* ctx_out  = out;                // N*D floats
    float* mask_out = out + N_ * D_;      // N*T floats

    float* energy_score = (float*)d_ws;                    // N*T floats (1MB)
    float* part         = energy_score + (size_t)N_ * T_;  // 64*32*2*128 floats (2MB)

    energy_kernel<<<2048, 256, 0, stream>>>(key, query, slen, energy_score);
    softmax_kernel<<<N_, 256, 0, stream>>>(energy_score, slen, mask_out);
    pv_kernel<<<2048, 256, 0, stream>>>(value, energy_score, part);
    ctx_reduce_kernel<<<N_, 128, 0, stream>>>(part, ctx_out);
}

// Round 11
// 259.262 us; speedup vs baseline: 1.1379x; 1.0350x over previous
//
#include <hip/hip_runtime.h>

// Shapes fixed by the reference.
#define N_  64
#define T_  4096
#define D_  128

// Non-temporal float4 load: stream past cache allocation (nt flag).
typedef float f4v __attribute__((ext_vector_type(4)));
__device__ __forceinline__ f4v nt_load4(const float* p) {
    return __builtin_nontemporal_load(reinterpret_cast<const f4v*>(p));
}

// ---------------------------------------------------------------------------
// Energy: e[n,t] = <key[t,n,:], q[n,:]>, masked (t>=len -> 0).
// Round-11 change vs round 10: SKIP the K load entirely when t >= len[n] —
// multiplicative mask makes those energies 0 regardless of K's contents,
// so the bytes are dead (~50% of K traffic on average, len ~ U[0,T)).
// Condition is uniform per half-wave (n fixed, t uniform across wave), so
// the compiler predicates the load via exec mask -> no memory request.
// NT loads kept (round-10: −20% kernel time, L3-allocate path throttles).
// One wave-load = 1KB contiguous: rows (t,n0) lanes 0-31, (t,n0+1) lanes
// 32-63. Wave w: npair = w&31, t walks 16 steps, 8-deep prefetch.
// ---------------------------------------------------------------------------
__global__ __launch_bounds__(256) void energy_kernel(
    const float* __restrict__ key, const float* __restrict__ query,
    const int* __restrict__ slen, float* __restrict__ energy)
{
    const int tid   = threadIdx.x;
    const int lane  = tid & 63;
    const int wv    = tid >> 6;
    const int w     = blockIdx.x * 4 + wv;
    const int npair = w & 31;
    const int t0    = (w >> 5) << 4;       // 16 t's per wave
    const int d4    = lane & 31;           // float4 index within row
    const int n     = npair * 2 + (lane >> 5);
    const int len   = slen[n];

    const float4 q4 = *reinterpret_cast<const float4*>(query + n * D_ + d4 * 4);
    const float* kbase = key + ((size_t)t0 * N_ + npair * 2) * D_ + lane * 4;
    const size_t st = (size_t)N_ * D_;     // t-stride in floats (32KB)

    f4v kb[8];
    #pragma unroll
    for (int g = 0; g < 2; ++g) {
        #pragma unroll
        for (int i = 0; i < 8; ++i) {
            const int t = t0 + g * 8 + i;
            // Dead-load elimination: masked t never influences the output.
            kb[i] = (t < len) ? nt_load4(kbase + (size_t)(g * 8 + i) * st)
                              : (f4v){0.f, 0.f, 0.f, 0.f};
        }
        #pragma unroll
        for (int i = 0; i < 8; ++i) {
            float p = kb[i][0] * q4.x + kb[i][1] * q4.y
                    + kb[i][2] * q4.z + kb[i][3] * q4.w;
            #pragma unroll
            for (int off = 16; off; off >>= 1) p += __shfl_xor(p, off, 64);
            const int t = t0 + g * 8 + i;
            if (d4 == 0) energy[(size_t)n * T_ + t] = (t < len) ? p : 0.f;
        }
    }
}

// ---------------------------------------------------------------------------
// Softmax over t per n (exact, in-place on energy buffer) + mask output.
// Masked positions hold 0 (multiplicative-mask semantics).
// ---------------------------------------------------------------------------
__global__ __launch_bounds__(256) void softmax_kernel(
    float* __restrict__ energy_score, const int* __restrict__ slen,
    float* __restrict__ mask_out)
{
    const int n    = blockIdx.x;
    const int len  = slen[n];
    const int tid  = threadIdx.x;
    const int lane = tid & 63;
    const int wv   = tid >> 6;

    float ev[T_ / 256];
    #pragma unroll
    for (int i = 0; i < T_ / 256; ++i)
        ev[i] = energy_score[(size_t)n * T_ + tid + i * 256];   // already masked

    float m = -3.4e38f;
    #pragma unroll
    for (int i = 0; i < T_ / 256; ++i) m = fmaxf(m, ev[i]);
    #pragma unroll
    for (int off = 32; off; off >>= 1) m = fmaxf(m, __shfl_xor(m, off, 64));
    __shared__ float wred[8];
    if (lane == 0) wred[wv] = m;
    __syncthreads();
    m = fmaxf(fmaxf(wred[0], wred[1]), fmaxf(wred[2], wred[3]));

    float s = 0.f;
    #pragma unroll
    for (int i = 0; i < T_ / 256; ++i) s += __expf(ev[i] - m);
    #pragma unroll
    for (int off = 32; off; off >>= 1) s += __shfl_xor(s, off, 64);
    if (lane == 0) wred[4 + wv] = s;
    __syncthreads();
    s = wred[4] + wred[5] + wred[6] + wred[7];
    const float inv = 1.f / s;

    #pragma unroll
    for (int i = 0; i < T_ / 256; ++i) {
        const int t = tid + i * 256;
        energy_score[(size_t)n * T_ + t] = __expf(ev[i] - m) * inv;
        mask_out[(size_t)n * T_ + t] = (t < len) ? 1.f : 0.f;
    }
}

// ---------------------------------------------------------------------------
// PV: part[c, npair, nl, :] = sum_{t in chunk c} score[n,t] * value[t,n,:].
// V loads NON-TEMPORAL; ALL t needed (multiplicative mask -> score > 0).
// ---------------------------------------------------------------------------
__global__ __launch_bounds__(256) void pv_kernel(
    const float* __restrict__ value, const float* __restrict__ score,
    float* __restrict__ part)
{
    const int b     = blockIdx.x;          // 2048 = 64 chunks x 32 npairs
    const int npair = b & 31;
    const int c     = b >> 5;              // t-chunk 0..63
    const int tid   = threadIdx.x;
    const int lane  = tid & 63;
    const int g     = tid >> 6;            // wave 0..3
    const int n     = npair * 2 + (lane >> 5);
    const int t0    = c * 64 + g * 16;

    const float* vbase = value + ((size_t)t0 * N_ + npair * 2) * D_ + lane * 4;
    const size_t st = (size_t)N_ * D_;

    float4 acc = make_float4(0.f, 0.f, 0.f, 0.f);
    f4v vb[8];
    #pragma unroll
    for (int gg = 0; gg < 2; ++gg) {
        #pragma unroll
        for (int i = 0; i < 8; ++i)
            vb[i] = nt_load4(vbase + (size_t)(gg * 8 + i) * st);
        #pragma unroll
        for (int i = 0; i < 8; ++i) {
            const float sc = score[(size_t)n * T_ + t0 + gg * 8 + i];  // L1/L2-hot
            acc.x += sc * vb[i][0]; acc.y += sc * vb[i][1];
            acc.z += sc * vb[i][2]; acc.w += sc * vb[i][3];
        }
    }

    __shared__ float4 red[4][64];
    red[g][lane] = acc;
    __syncthreads();
    if (tid < 64) {
        const float4 a = red[0][tid], bb = red[1][tid];
        const float4 cc = red[2][tid], dd = red[3][tid];
        float4 r;
        r.x = (a.x + bb.x) + (cc.x + dd.x);
        r.y = (a.y + bb.y) + (cc.y + dd.y);
        r.z = (a.z + bb.z) + (cc.z + dd.z);
        r.w = (a.w + bb.w) + (cc.w + dd.w);
        *reinterpret_cast<float4*>(part + ((size_t)b * 2 + (tid >> 5)) * D_
                                        + (tid & 31) * 4) = r;
    }
}

// ---------------------------------------------------------------------------
// Final reduce: ctx[n,:] = sum_c part[c, n>>1, n&1, :]  (score pre-normalized).
// ---------------------------------------------------------------------------
__global__ __launch_bounds__(128) void ctx_reduce_kernel(
    const float* __restrict__ part, float* __restrict__ ctx)
{
    const int n = blockIdx.x;
    const int d = threadIdx.x;
    const int npair = n >> 1, nl = n & 1;
    float a = 0.f;
    #pragma unroll 8
    for (int c = 0; c < 64; ++c)
        a += part[(((size_t)c * 32 + npair) * 2 + nl) * D_ + d];
    ctx[(size_t)n * D_ + d] = a;
}

// ---------------------------------------------------------------------------
extern "C" void kernel_launch(void* const* d_in, const int* in_sizes, int n_in,
                              void* d_out, int out_size, void* d_ws, size_t ws_size,
                              hipStream_t stream) {
    const float* query = (const float*)d_in[0];   // (N, D)
    const float* key   = (const float*)d_in[1];   // (T, N, D)
    const float* value = (const float*)d_in[2];   // (T, N, D)
    const int*   slen  = (const int*)d_in[3];     // (N,)

    float* out      = (float*)d_out;
    float* ctx_out  = out;                // N*D floats
    float* mask_out = out + N_ * D_;      // N*T floats

    float* energy_score = (float*)d_ws;                    // N*T floats (1MB)
    float* part         = energy_score + (size_t)N_ * T_;  // 64*32*2*128 floats (2MB)

    energy_kernel<<<2048, 256, 0, stream>>>(key, query, slen, energy_score);
    softmax_kernel<<<N_, 256, 0, stream>>>(energy_score, slen, mask_out);
    pv_kernel<<<2048, 256, 0, stream>>>(value, energy_score, part);
    ctx_reduce_kernel<<<N_, 128, 0, stream>>>(part, ctx_out);
}

// Round 12
// 251.274 us; speedup vs baseline: 1.1741x; 1.0318x over previous
//
#include <hip/hip_runtime.h>

// Shapes fixed by the reference.
#define N_  64
#define T_  4096
#define D_  128
#define CH_ 64            // t-chunks (64 t per chunk)
#define TC_ (T_ / CH_)    // 64

// Non-temporal float4 load: stream past cache allocation (nt flag).
typedef float f4v __attribute__((ext_vector_type(4)));
__device__ __forceinline__ f4v nt_load4(const float* p) {
    return __builtin_nontemporal_load(reinterpret_cast<const f4v*>(p));
}

// ---------------------------------------------------------------------------
// Fused flash pass. Block b = (npair, c): rows n0=2*npair, n0+1, t in
// [c*64, c*64+64). 256 threads = 4 waves; wave wv owns 16 t's.
// Proven ingredients from rounds 9-11 (each A/B-verified):
//   * single-segment 1KB wave-loads (lanes 0-31 -> row (t,n0), 32-63 -> (t,n0+1))
//   * non-temporal K/V loads (round 10: -20% kernel time)
//   * K dead-load skip for t >= len (round 11: -10%)
// New vs round 11: softmax fused in-block (per-chunk m,s partials merged by
// finalize) -- kills the softmax kernel, the score round-trip, 2 launches.
// V loads are issued BEFORE the softmax phase so HBM latency hides under it.
// ---------------------------------------------------------------------------
__global__ __launch_bounds__(256) void fused_kernel(
    const float* __restrict__ key, const float* __restrict__ value,
    const float* __restrict__ query, const int* __restrict__ slen,
    float* __restrict__ mask_out, float* __restrict__ m_ws,
    float* __restrict__ s_ws, float* __restrict__ acc_ws)
{
    const int b     = blockIdx.x;          // 2048 = 32 npairs x 64 chunks
    const int npair = b & 31;
    const int c     = b >> 5;
    const int tid   = threadIdx.x;
    const int lane  = tid & 63;
    const int wv    = tid >> 6;            // 0..3
    const int nl    = lane >> 5;           // which n of the pair
    const int d4    = lane & 31;           // float4 index within row
    const int n     = npair * 2 + nl;
    const int len   = slen[n];
    const int t0    = c * 64 + wv * 16;    // this wave's t range

    __shared__ float  ep[2][64];           // p values per (n-of-pair, local t)
    __shared__ float4 red[4][64];          // V-accum cross-wave reduce

    const float4 q4 = *reinterpret_cast<const float4*>(query + n * D_ + d4 * 4);
    const size_t st = (size_t)N_ * D_;     // t-stride in floats (32KB)
    const float* kbase = key   + ((size_t)t0 * N_ + npair * 2) * D_ + lane * 4;
    const float* vbase = value + ((size_t)t0 * N_ + npair * 2) * D_ + lane * 4;

    // ---- phase 1: K loads (skip masked t) + energies ----
    f4v kb[16];
    #pragma unroll
    for (int i = 0; i < 16; ++i) {
        const int t = t0 + i;
        kb[i] = (t < len) ? nt_load4(kbase + (size_t)i * st)
                          : (f4v){0.f, 0.f, 0.f, 0.f};
    }
    #pragma unroll
    for (int i = 0; i < 16; ++i) {
        float p = kb[i][0] * q4.x + kb[i][1] * q4.y
                + kb[i][2] * q4.z + kb[i][3] * q4.w;
        #pragma unroll
        for (int off = 16; off; off >>= 1) p += __shfl_xor(p, off, 64);
        const int t = t0 + i;
        if (d4 == 0) ep[nl][wv * 16 + i] = (t < len) ? p : 0.f;
    }

    // ---- issue ALL V loads now; latency hides under the softmax phase ----
    f4v vb[16];
    #pragma unroll
    for (int i = 0; i < 16; ++i)
        vb[i] = nt_load4(vbase + (size_t)i * st);

    __syncthreads();                       // publishes ep[] (masked energies)

    // ---- phase 2: per-n chunk softmax partial (waves 0,1); mask (2,3) ----
    if (wv < 2) {
        const float e = ep[wv][lane];
        float m = e;
        #pragma unroll
        for (int off = 32; off; off >>= 1) m = fmaxf(m, __shfl_xor(m, off, 64));
        const float p = __expf(e - m);
        float s = p;
        #pragma unroll
        for (int off = 32; off; off >>= 1) s += __shfl_xor(s, off, 64);
        ep[wv][lane] = p;                  // published by barrier below
        if (lane == 0) {
            m_ws[(npair * 2 + wv) * CH_ + c] = m;
            s_ws[(npair * 2 + wv) * CH_ + c] = s;
        }
    } else {
        const int nn = npair * 2 + (wv - 2);
        const int t  = c * 64 + lane;
        mask_out[(size_t)nn * T_ + t] = (t < slen[nn]) ? 1.f : 0.f;
    }
    __syncthreads();

    // ---- phase 3: weighted V accumulation (V already in registers) ----
    float4 acc = make_float4(0.f, 0.f, 0.f, 0.f);
    #pragma unroll
    for (int i = 0; i < 16; ++i) {
        const float pv = ep[nl][wv * 16 + i];
        acc.x += pv * vb[i][0]; acc.y += pv * vb[i][1];
        acc.z += pv * vb[i][2]; acc.w += pv * vb[i][3];
    }
    red[wv][lane] = acc;
    __syncthreads();
    if (tid < 64) {
        const float4 a = red[0][tid], bb = red[1][tid];
        const float4 cc = red[2][tid], dd = red[3][tid];
        float4 r;
        r.x = (a.x + bb.x) + (cc.x + dd.x);
        r.y = (a.y + bb.y) + (cc.y + dd.y);
        r.z = (a.z + bb.z) + (cc.z + dd.z);
        r.w = (a.w + bb.w) + (cc.w + dd.w);
        // tid = nl*32 + d4
        *reinterpret_cast<float4*>(
            acc_ws + ((size_t)(npair * 2 + (tid >> 5)) * CH_ + c) * D_
                   + (tid & 31) * 4) = r;
    }
}

// ---------------------------------------------------------------------------
// Finalize: per n merge 64 chunk partials (standard flash merge).
//   M = max_c m_c; w_c = exp(m_c-M); S = sum_c s_c*w_c;
//   ctx[n,:] = (1/S) * sum_c w_c * acc[n,c,:]
// 64 blocks x 64 threads (one wave). Lane = d-pair; w_c broadcast via shfl.
// ---------------------------------------------------------------------------
__global__ __launch_bounds__(64) void finalize_kernel(
    const float* __restrict__ m_ws, const float* __restrict__ s_ws,
    const float* __restrict__ acc_ws, float* __restrict__ ctx)
{
    const int n    = blockIdx.x;
    const int lane = threadIdx.x;

    const float mc = m_ws[n * CH_ + lane];       // CH_ == 64 == wave size
    float M = mc;
    #pragma unroll
    for (int off = 32; off; off >>= 1) M = fmaxf(M, __shfl_xor(M, off, 64));

    const float w = __expf(mc - M);
    float S = s_ws[n * CH_ + lane] * w;
    #pragma unroll
    for (int off = 32; off; off >>= 1) S += __shfl_xor(S, off, 64);

    const float2* acc2 = reinterpret_cast<const float2*>(acc_ws);
    float2 r = make_float2(0.f, 0.f);
    #pragma unroll 8
    for (int c = 0; c < CH_; ++c) {
        const float wc = __shfl(w, c, 64);
        const float2 a = acc2[((size_t)n * CH_ + c) * (D_ / 2) + lane];
        r.x += wc * a.x; r.y += wc * a.y;
    }
    const float invS = 1.f / S;
    *reinterpret_cast<float2*>(ctx + (size_t)n * D_ + lane * 2) =
        make_float2(r.x * invS, r.y * invS);
}

// ---------------------------------------------------------------------------
extern "C" void kernel_launch(void* const* d_in, const int* in_sizes, int n_in,
                              void* d_out, int out_size, void* d_ws, size_t ws_size,
                              hipStream_t stream) {
    const float* query = (const float*)d_in[0];   // (N, D)
    const float* key   = (const float*)d_in[1];   // (T, N, D)
    const float* value = (const float*)d_in[2];   // (T, N, D)
    const int*   slen  = (const int*)d_in[3];     // (N,)

    float* out      = (float*)d_out;
    float* ctx_out  = out;                // N*D floats
    float* mask_out = out + N_ * D_;      // N*T floats

    float* m_ws   = (float*)d_ws;                 // N*CH floats
    float* s_ws   = m_ws + N_ * CH_;              // N*CH floats
    float* acc_ws = s_ws + N_ * CH_;              // N*CH*D floats (2MB)

    fused_kernel<<<32 * CH_, 256, 0, stream>>>(key, value, query, slen,
                                               mask_out, m_ws, s_ws, acc_ws);
    finalize_kernel<<<N_, 64, 0, stream>>>(m_ws, s_ws, acc_ws, ctx_out);
}